// Round 7
// baseline (95.614 us; speedup 1.0000x reference)
//
#include <hip/hip_runtime.h>

// Blockwise int8 dequant: out[i] = code[w[i] & 255] * absmax[i / 4096]
// w: [64Mi] int32 codes in [0,256); absmax: [16384] f32; code: [256] f32.
// Memory-bound stream: 256 MB read + 256 MB write.
// R6: single chain (1 read stream + 1 write stream) to maximize DRAM page
//     locality; nt loads (no L2 alloc) + plain stores (L2 write-combine).

typedef int   int4v   __attribute__((ext_vector_type(4)));
typedef float float4v __attribute__((ext_vector_type(4)));

__global__ __launch_bounds__(256) void dequant_blockwise_kernel(
    const int* __restrict__ w,
    const float* __restrict__ absmax,
    const float* __restrict__ code,
    float* __restrict__ out,
    long n4)  // number of vec4 elements (n / 4)
{
    __shared__ float lcode[256];
    lcode[threadIdx.x] = code[threadIdx.x];
    __syncthreads();

    const int4v* w4   = reinterpret_cast<const int4v*>(w);
    float4v*     out4 = reinterpret_cast<float4v*>(out);

    const long nthreads = (long)gridDim.x * blockDim.x;
    const long tid      = (long)blockIdx.x * blockDim.x + threadIdx.x;

    for (long i = tid; i < n4; i += nthreads) {
        int4v wv = __builtin_nontemporal_load(w4 + i);
        float am = absmax[i >> 10];   // 1024 vec4 per absmax block
        float4v o;
        o.x = lcode[wv.x & 255] * am;
        o.y = lcode[wv.y & 255] * am;
        o.z = lcode[wv.z & 255] * am;
        o.w = lcode[wv.w & 255] * am;
        out4[i] = o;                  // plain store: L2 write-combine path
    }
}

extern "C" void kernel_launch(void* const* d_in, const int* in_sizes, int n_in,
                              void* d_out, int out_size, void* d_ws, size_t ws_size,
                              hipStream_t stream) {
    const int*   w      = (const int*)d_in[0];
    const float* absmax = (const float*)d_in[1];
    const float* code   = (const float*)d_in[2];
    float*       out    = (float*)d_out;

    const long n  = (long)in_sizes[0];  // 8192*8192 = 67,108,864
    const long n4 = n >> 2;             // 16Mi vec4

    const int threads = 256;
    const int blocks  = 2048;           // 512Ki threads; 32 vec4/thread
    dequant_blockwise_kernel<<<blocks, threads, 0, stream>>>(w, absmax, code, out, n4);
}

// Round 8
// 95.588 us; speedup vs baseline: 1.0003x; 1.0003x over previous
//
#include <hip/hip_runtime.h>

// Blockwise int8 dequant: out[i] = code[w[i] & 255] * absmax[i / 4096]
// w: [64Mi] int32 codes in [0,256); absmax: [16384] f32; code: [256] f32.
// Memory-bound stream: 256 MB read + 256 MB write.
// R7 == R5 (best: 90.2 us, 5.95 TB/s = 94.5% of copy ceiling):
//   - nt LOADS: read stream bypasses L2 allocation (never re-read)
//   - PLAIN stores: L2 write-combining (nt stores cost ~6%)
//   - 2 grid-stride-separated chains: 32 B/thread in flight (1 chain: +6%,
//     4 chains: worse page locality, +17% in the nt-store regime)
//   - grid 2048x256 = max occupancy (8192 waves = 32/CU exactly)

typedef int   int4v   __attribute__((ext_vector_type(4)));
typedef float float4v __attribute__((ext_vector_type(4)));

__global__ __launch_bounds__(256) void dequant_blockwise_kernel(
    const int* __restrict__ w,
    const float* __restrict__ absmax,
    const float* __restrict__ code,
    float* __restrict__ out,
    long n4)  // number of vec4 elements (n / 4)
{
    __shared__ float lcode[256];
    lcode[threadIdx.x] = code[threadIdx.x];
    __syncthreads();

    const int4v* w4   = reinterpret_cast<const int4v*>(w);
    float4v*     out4 = reinterpret_cast<float4v*>(out);

    const long nthreads = (long)gridDim.x * blockDim.x;
    const long tid      = (long)blockIdx.x * blockDim.x + threadIdx.x;

    long i = tid;
    for (; i + nthreads < n4; i += 2 * nthreads) {
        const long i0 = i;
        const long i1 = i + nthreads;

        int4v w0 = __builtin_nontemporal_load(w4 + i0);
        int4v w1 = __builtin_nontemporal_load(w4 + i1);

        float am0 = absmax[i0 >> 10];
        float am1 = absmax[i1 >> 10];

        float4v o0, o1;
        o0.x = lcode[w0.x & 255] * am0;
        o0.y = lcode[w0.y & 255] * am0;
        o0.z = lcode[w0.z & 255] * am0;
        o0.w = lcode[w0.w & 255] * am0;
        o1.x = lcode[w1.x & 255] * am1;
        o1.y = lcode[w1.y & 255] * am1;
        o1.z = lcode[w1.z & 255] * am1;
        o1.w = lcode[w1.w & 255] * am1;

        out4[i0] = o0;   // plain store: L2 write-combine path
        out4[i1] = o1;
    }
    // Tail (not taken for 64Mi elems with 2048x256 grid, kept for safety).
    for (; i < n4; i += nthreads) {
        int4v w0 = __builtin_nontemporal_load(w4 + i);
        float am0 = absmax[i >> 10];
        float4v o0;
        o0.x = lcode[w0.x & 255] * am0;
        o0.y = lcode[w0.y & 255] * am0;
        o0.z = lcode[w0.z & 255] * am0;
        o0.w = lcode[w0.w & 255] * am0;
        out4[i] = o0;
    }
}

extern "C" void kernel_launch(void* const* d_in, const int* in_sizes, int n_in,
                              void* d_out, int out_size, void* d_ws, size_t ws_size,
                              hipStream_t stream) {
    const int*   w      = (const int*)d_in[0];
    const float* absmax = (const float*)d_in[1];
    const float* code   = (const float*)d_in[2];
    float*       out    = (float*)d_out;

    const long n  = (long)in_sizes[0];  // 8192*8192 = 67,108,864
    const long n4 = n >> 2;             // 16Mi vec4

    const int threads = 256;
    const int blocks  = 2048;           // 512Ki threads; 32 vec4/thread
    dequant_blockwise_kernel<<<blocks, threads, 0, stream>>>(w, absmax, code, out, n4);
}